// Round 9
// baseline (40.729 us; speedup 1.0000x reference)
//
#include <hip/hip_runtime.h>
#include <hip/hip_fp16.h>

// out[m][n] = fp16( fp16( (sum_k x[m][k]*w6[n][k]) * scale[n] ) + bias[n] ), stored fp32
// Inputs pushed as fp32 (fp16-exact) -> cvt fp16 (exact), f16 MFMA, fp32 acc.
// v9: 128x128 tile (halves L2 traffic 512->268MB and LDS 768->527MB vs 64x64),
// BK=64, double-buffered fp16 LDS with ONE barrier/phase, load-early single-region
// loop (loads at top, cvt+ds_write after MFMA -> compiler hides latency in-region),
// split-K x4 streamed partials (no atomics), XCD swizzle.

typedef __attribute__((ext_vector_type(8))) _Float16 half8;
typedef __attribute__((ext_vector_type(2))) __fp16 fp16x2;  // cvt_pkrtz return type
typedef __attribute__((ext_vector_type(4))) float f32x4;

constexpr int K  = 4096;
constexpr int N  = 4096;
constexpr int M  = 256;
constexpr int BM = 128;
constexpr int BN = 128;
constexpr int BK = 64;
constexpr int SPL  = 4;
constexpr int KSPL = K / SPL;       // 1024
constexpr int NT   = KSPL / BK;     // 16 phases
constexpr int LDH  = BK + 8;        // 72 halves = 144B row stride (2-way-free frag reads)
constexpr int OPH  = BM * LDH;      // 9216 halves per op-tile

__device__ __forceinline__ half8 pack8(float4 a, float4 b) {
    fp16x2 p0 = __builtin_amdgcn_cvt_pkrtz(a.x, a.y);   // exact: inputs fp16-exact
    fp16x2 p1 = __builtin_amdgcn_cvt_pkrtz(a.z, a.w);
    fp16x2 p2 = __builtin_amdgcn_cvt_pkrtz(b.x, b.y);
    fp16x2 p3 = __builtin_amdgcn_cvt_pkrtz(b.z, b.w);
    half8 h;
    h[0] = (_Float16)p0[0]; h[1] = (_Float16)p0[1];
    h[2] = (_Float16)p1[0]; h[3] = (_Float16)p1[1];
    h[4] = (_Float16)p2[0]; h[5] = (_Float16)p2[1];
    h[6] = (_Float16)p3[0]; h[7] = (_Float16)p3[1];
    return h;
}

__global__ __launch_bounds__(512, 2)
void fp6lin_gemm(const float* __restrict__ X,
                 const float* __restrict__ W,
                 float* __restrict__ P)      // [SPL][M][N] fp32 partials
{
    __shared__ __align__(16) _Float16 LA[2][OPH];   // x tiles, 36,864 B
    __shared__ __align__(16) _Float16 LB[2][OPH];   // w tiles, 36,864 B

    const int tid  = (int)threadIdx.x;
    const int lane = tid & 63;
    const int wid  = tid >> 6;          // 8 waves: 2 (M) x 4 (N), wave tile 64x32
    const int wm   = (wid & 1) * 64;
    const int wn   = (wid >> 1) * 32;

    // XCD swizzle: grid 256 = 8 XCDs x 32. Within an XCD: bm fastest (the 2 blocks
    // sharing a W k-panel co-resident), then sp, then bn (X slice L2-hot).
    const int bid   = (int)blockIdx.x;
    const int xcd   = bid & 7;
    const int idx   = bid >> 3;             // 0..31
    const int bm    = (idx & 1) * BM;       // 2 M-tiles
    const int combo = xcd * 16 + (idx >> 1);// 0..127
    const int sp    = combo & 3;            // 4 K-splits
    const int bn    = (combo >> 2) * BN;    // 32 N-tiles
    const int kb    = sp * KSPL;

    // staging map: thread t -> row t>>2 (0..127), 16 consecutive floats at (t&3)*16.
    // 4 consecutive lanes cover one 256B row segment -> coalesced.
    const int srow = tid >> 2;
    const int scol = (tid & 3) * 16;
    const float* xp = X + (size_t)(bm + srow) * K + kb + scol;
    const float* wp = W + (size_t)(bn + srow) * K + kb + scol;
    const int stOff = srow * LDH + scol;

    // frag read offsets (16x16x32 layout: row=lane&15, k=(lane>>4)*8+j)
    const int paOff = (wm + (lane & 15)) * LDH + ((lane >> 4) << 3);
    const int pbOff = (wn + (lane & 15)) * LDH + ((lane >> 4) << 3);

    f32x4 acc[4][2];
    #pragma unroll
    for (int a = 0; a < 4; ++a)
        #pragma unroll
        for (int b = 0; b < 2; ++b)
            acc[a][b] = (f32x4){0.f, 0.f, 0.f, 0.f};

    // named stage slots (single region: loads at top of phase, consumed after MFMA)
    float4 xa0, xa1, xa2, xa3, wa0, wa1, wa2, wa3;

#define LOADR(t) do { const float* xq = xp + (t) * BK; const float* wq = wp + (t) * BK; \
        xa0 = *(const float4*)(xq);      xa1 = *(const float4*)(xq + 4);               \
        xa2 = *(const float4*)(xq + 8);  xa3 = *(const float4*)(xq + 12);              \
        wa0 = *(const float4*)(wq);      wa1 = *(const float4*)(wq + 4);               \
        wa2 = *(const float4*)(wq + 8);  wa3 = *(const float4*)(wq + 12); } while (0)
#define STORE(bf) do {                                                  \
        *(half8*)(&LA[bf][stOff])     = pack8(xa0, xa1);                \
        *(half8*)(&LA[bf][stOff + 8]) = pack8(xa2, xa3);                \
        *(half8*)(&LB[bf][stOff])     = pack8(wa0, wa1);                \
        *(half8*)(&LB[bf][stOff + 8]) = pack8(wa2, wa3); } while (0)
#define COMPUTE(bf) do {                                                \
        _Pragma("unroll")                                               \
        for (int kk = 0; kk < 2; ++kk) {                                \
            half8 af[4]; half8 bf2[2];                                  \
            _Pragma("unroll")                                           \
            for (int ar = 0; ar < 4; ++ar)                              \
                af[ar] = *(const half8*)(&LA[bf][paOff + ar * 16 * LDH + kk * 32]); \
            _Pragma("unroll")                                           \
            for (int br = 0; br < 2; ++br)                              \
                bf2[br] = *(const half8*)(&LB[bf][pbOff + br * 16 * LDH + kk * 32]); \
            _Pragma("unroll")                                           \
            for (int ar = 0; ar < 4; ++ar)                              \
                _Pragma("unroll")                                       \
                for (int br = 0; br < 2; ++br)                          \
                    acc[ar][br] = __builtin_amdgcn_mfma_f32_16x16x32_f16(          \
                        af[ar], bf2[br], acc[ar][br], 0, 0, 0);         \
        } } while (0)

    // prologue: tile 0 -> buf 0 (one unavoidable drain)
    LOADR(0);
    STORE(0);
    __syncthreads();

    for (int t = 0; t < NT; ++t) {
        const int tn = (t + 1 < NT) ? t + 1 : t;   // branchless tail (redundant reload)
        LOADR(tn);                 // issue early; vmcnt waited only at STORE below
        COMPUTE(t & 1);            // ds_read + MFMA, no vmem -> hides load latency
        STORE((t + 1) & 1);        // cvt (waits loads) + ds_write into other buffer
        __syncthreads();           // single barrier per phase (dbuf)
    }
#undef LOADR
#undef STORE
#undef COMPUTE

    // streamed partial stores. C/D: col=lane&15, row=(lane>>4)*4+reg [m89/m91]
    float* Pb = P + (size_t)sp * M * N;
    const int orow = bm + wm + ((lane >> 4) << 2);
    const int ocol = bn + wn + (lane & 15);
    #pragma unroll
    for (int ar = 0; ar < 4; ++ar)
        #pragma unroll
        for (int br = 0; br < 2; ++br)
            #pragma unroll
            for (int r = 0; r < 4; ++r)
                Pb[(size_t)(orow + ar * 16 + r) * N + ocol + br * 16] = acc[ar][br][r];
}

// O = fp32( fp16( fp16( (sum of SPL partials) * scale[n] ) + bias[n] ) )
template <int SPLT>
__global__ __launch_bounds__(256)
void fp6lin_finalize(const float* __restrict__ P,
                     const float* __restrict__ S,
                     const float* __restrict__ Bi,
                     float* __restrict__ O)
{
    const size_t i = ((size_t)blockIdx.x * 256 + threadIdx.x) * 4;
    const int n = (int)(i & (N - 1));
    float4 v = *(const float4*)(P + i);
    #pragma unroll
    for (int s = 1; s < SPLT; ++s) {
        float4 u = *(const float4*)(P + (size_t)s * M * N + i);
        v.x += u.x; v.y += u.y; v.z += u.z; v.w += u.w;
    }
    float4 sc = *(const float4*)(S + n);
    float4 bb = *(const float4*)(Bi + n);
    v.x = (float)(_Float16)((float)(_Float16)(v.x * sc.x) + bb.x);
    v.y = (float)(_Float16)((float)(_Float16)(v.y * sc.y) + bb.y);
    v.z = (float)(_Float16)((float)(_Float16)(v.z * sc.z) + bb.z);
    v.w = (float)(_Float16)((float)(_Float16)(v.w * sc.w) + bb.w);
    *(float4*)(O + i) = v;
}

// correctness fallback if d_ws is too small for 4 partial slices (shouldn't trigger)
__global__ __launch_bounds__(256)
void fp6lin_small(const float* __restrict__ X, const float* __restrict__ W,
                  const float* __restrict__ S, const float* __restrict__ Bi,
                  float* __restrict__ O)
{
    const int n = (int)blockIdx.x;
    const int m = (int)threadIdx.x;
    float s = 0.f;
    for (int k = 0; k < K; ++k)
        s += (float)(_Float16)X[(size_t)m * K + k] * (float)(_Float16)W[(size_t)n * K + k];
    O[(size_t)m * N + n] = (float)(_Float16)((float)(_Float16)(s * S[n]) + Bi[n]);
}

extern "C" void kernel_launch(void* const* d_in, const int* in_sizes, int n_in,
                              void* d_out, int out_size, void* d_ws, size_t ws_size,
                              hipStream_t stream) {
    const float* x  = (const float*)d_in[0];
    const float* w  = (const float*)d_in[1];
    const float* s  = (const float*)d_in[2];
    const float* bi = (const float*)d_in[3];
    float* o  = (float*)d_out;
    float* ws = (float*)d_ws;

    const size_t slice = (size_t)M * N * sizeof(float);   // 4 MB

    if (ws_size >= SPL * slice) {
        fp6lin_gemm<<<dim3(2 * 32 * SPL), dim3(512), 0, stream>>>(x, w, ws);
        fp6lin_finalize<SPL><<<dim3(M * N / 4 / 256), dim3(256), 0, stream>>>(ws, s, bi, o);
    } else {
        fp6lin_small<<<dim3(N), dim3(M), 0, stream>>>(x, w, s, bi, o);
    }
}